// Round 14
// baseline (321.145 us; speedup 1.0000x reference)
//
#include <hip/hip_runtime.h>
#include <hip/hip_cooperative_groups.h>
#include <math.h>

#define B_  8
#define S_  2048
#define D_  256
#define H_  4
#define DH  64
#define M_  (B_ * S_)          // 16384 rows
#define QS  4194304            // M_ * D_ elements

typedef __attribute__((ext_vector_type(8))) short bf16x8;   // 8 bf16 = 4 VGPRs
typedef __attribute__((ext_vector_type(4))) float f32x4;
typedef unsigned short u16;
typedef unsigned int   u32;

#define AS1 __attribute__((address_space(1)))
#define AS3 __attribute__((address_space(3)))

__device__ __forceinline__ u16 f2bf(float x) {
    union { float f; u32 u; } c; c.f = x;
    u32 r = (c.u + 0x7fffu + ((c.u >> 16) & 1u)) >> 16;   // RNE
    return (u16)r;
}
__device__ __forceinline__ float bf2f(u16 x) {
    union { u32 u; float f; } c; c.u = ((u32)x) << 16;
    return c.f;
}

// async global->LDS, 16B per lane; LDS dest = wave-uniform base + lane*16
__device__ __forceinline__ void gload16(const void* g, void* l) {
    __builtin_amdgcn_global_load_lds((const AS1 unsigned int*)g,
                                     (AS3 unsigned int*)l, 16, 0, 0);
}

// ---------------------------------------------------------------------------
// cast7: casts + W1 split + bias' fold + Wfused — ALL setup in ONE launch.
// Block ranges:
//   [0,4096)     desc cast
//   [4096,4288)  Wqkv cast
//   [4288,4544)  W1 cast (LEFT half -> w1f cols<256)
//   [4544,4672)  W2 cast
//   [4672,5184)  bias' fold: block n -> bias1f[n] = W1b[n]·Wo_b + W1_b[n]
//   [5184,5696)  Wfused: block row -> w1f[row][256+col] = W1b[row]·Wo[:,col]
// ---------------------------------------------------------------------------
__global__ __launch_bounds__(256) void cast7_kernel(
    const float* __restrict__ desc, u16* __restrict__ descb,
    const float* __restrict__ wqkv, u16* __restrict__ wqkvb,
    const float* __restrict__ wo,   const float* __restrict__ w1,
    u16* __restrict__ w1f,
    const float* __restrict__ w2,   u16* __restrict__ w2b,
    const float* __restrict__ w1_b, const float* __restrict__ wo_b,
    float* __restrict__ bias1f)
{
    int bid = blockIdx.x;
    const int tid = threadIdx.x;

    if (bid >= 5184) {          // Wfused: row = bid-5184, col = tid
        const int row = bid - 5184;
        const int col = tid;
        const float* wrow = w1 + (size_t)row * 512 + 256;   // uniform scalar reads
        float acc = 0.f;
#pragma unroll 4
        for (int k = 0; k < 256; k++)
            acc += wrow[k] * wo[(size_t)k * 256 + col];     // Wo coalesced, L2-hot
        w1f[(size_t)row * 512 + 256 + col] = f2bf(acc);
        return;
    }
    if (bid >= 4672) {          // bias' fold: block n, coalesced 256-dot
        __shared__ float red[4];
        const int n = bid - 4672;
        float p = w1[(size_t)n * 512 + 256 + tid] * wo_b[tid];
#pragma unroll
        for (int off = 1; off < 64; off <<= 1) p += __shfl_xor(p, off);
        if ((tid & 63) == 0) red[tid >> 6] = p;
        __syncthreads();
        if (tid == 0) bias1f[n] = red[0] + red[1] + red[2] + red[3] + w1_b[n];
        return;
    }
    if (bid >= 4544) {          // W2 cast
        const int i = ((bid - 4544) * 256 + tid) * 4;
        const float4 v = *(const float4*)(w2 + i);
        u16 o[4] = {f2bf(v.x), f2bf(v.y), f2bf(v.z), f2bf(v.w)};
        *(uint2*)(w2b + i) = *(const uint2*)o;
        return;
    }
    if (bid >= 4288) {          // W1 cast: LEFT half only -> w1f cols<256
        const int e = ((bid - 4288) * 256 + tid) * 4;
        const int row = e >> 9, col = e & 511;
        if (col < 256) {
            const float4 v = *(const float4*)(w1 + e);
            u16 o[4] = {f2bf(v.x), f2bf(v.y), f2bf(v.z), f2bf(v.w)};
            *(uint2*)(w1f + (size_t)row * 512 + col) = *(const uint2*)o;
        }
        return;
    }
    // desc or Wqkv
    const float* s; u16* d;
    if (bid < 4096) { s = desc; d = descb; }
    else            { s = wqkv; d = wqkvb; bid -= 4096; }
    const int i = (bid * 256 + tid) * 4;
    const float4 v = *(const float4*)(s + i);
    u16 o[4] = {f2bf(v.x), f2bf(v.y), f2bf(v.z), f2bf(v.w)};
    *(uint2*)(d + i) = *(const uint2*)o;
}

// ---------------------------------------------------------------------------
// bf16 MFMA GEMM (m97 structure): C = A*W^T + bias.
// Tile 128 x (NT*32), BK=64, 256 thr (4 waves, 2x2 wave grid). 2D grid.
// ---------------------------------------------------------------------------
template <int NT, int CONCAT, int RES, int OUTBF16>
__global__ __launch_bounds__(256) void gemm_bf16(
    const u16* __restrict__ A, const u16* __restrict__ A2,
    const u16* __restrict__ W, const float* __restrict__ bias,
    const float* __restrict__ res, float* __restrict__ Cf,
    u16* __restrict__ Cb, int K, int N, int ldc)
{
    __shared__ u16 As[128 * 64];
    __shared__ u16 Bs[NT * 32 * 64];
    const int tid  = threadIdx.x;
    const int w    = tid >> 6;
    const int lane = tid & 63;
    const int n    = lane & 15;
    const int quad = lane >> 4;
    const int m0   = blockIdx.x * 128;
    const int n0   = blockIdx.y * (NT * 32);
    const int m_off = (w >> 1) * 64;
    const int n_off = (w & 1) * (NT * 16);
    const int lrow = lane >> 3;          // 0..7
    const int lcol = (lane & 7) * 8;     // bf16 elem offset

    f32x4 acc[4][NT];
#pragma unroll
    for (int i = 0; i < 4; i++)
#pragma unroll
        for (int j = 0; j < NT; j++) acc[i][j] = (f32x4){0.f, 0.f, 0.f, 0.f};

    for (int k0 = 0; k0 < K; k0 += 64) {
        const u16* Asrc;
        int kb, lda;
        if (CONCAT) { Asrc = (k0 < 256) ? A : A2; kb = k0 & 255; lda = 256; }
        else        { Asrc = A; kb = k0; lda = K; }

        __syncthreads();
#pragma unroll
        for (int it = 0; it < 4; it++) {
            const int r0 = it * 32 + w * 8;      // wave-uniform
            gload16(Asrc + (size_t)(m0 + r0 + lrow) * lda + kb + lcol, &As[r0 * 64]);
        }
#pragma unroll
        for (int it = 0; it < NT; it++) {
            const int r0 = it * 32 + w * 8;
            gload16(W + (size_t)(n0 + r0 + lrow) * K + k0 + lcol, &Bs[r0 * 64]);
        }
        __syncthreads();

        bf16x8 af[4][2], bf[NT][2];
#pragma unroll
        for (int mt = 0; mt < 4; mt++)
#pragma unroll
            for (int t = 0; t < 2; t++)
                af[mt][t] = *(const bf16x8*)&As[(m_off + mt * 16 + n) * 64 + t * 32 + quad * 8];
#pragma unroll
        for (int nt = 0; nt < NT; nt++)
#pragma unroll
            for (int t = 0; t < 2; t++)
                bf[nt][t] = *(const bf16x8*)&Bs[(n_off + nt * 16 + n) * 64 + t * 32 + quad * 8];

#pragma unroll
        for (int mt = 0; mt < 4; mt++)
#pragma unroll
            for (int nt = 0; nt < NT; nt++) {
                acc[mt][nt] = __builtin_amdgcn_mfma_f32_16x16x32_bf16(af[mt][0], bf[nt][0], acc[mt][nt], 0, 0, 0);
                acc[mt][nt] = __builtin_amdgcn_mfma_f32_16x16x32_bf16(af[mt][1], bf[nt][1], acc[mt][nt], 0, 0, 0);
            }
    }

#pragma unroll
    for (int nt = 0; nt < NT; nt++) {
        const int col = n0 + n_off + nt * 16 + n;
        const float bv = bias[col];
#pragma unroll
        for (int mt = 0; mt < 4; mt++) {
#pragma unroll
            for (int r = 0; r < 4; r++) {
                const int row = m0 + m_off + mt * 16 + quad * 4 + r;
                float o = acc[mt][nt][r] + bv;
                if (RES) o += res[(size_t)row * ldc + col];
                if (OUTBF16) Cb[(size_t)row * ldc + col] = f2bf(o);
                else         Cf[(size_t)row * ldc + col] = o;
            }
        }
    }
}

// ---------------------------------------------------------------------------
// ropeattn: cooperative fusion of ropevt + flash attention v9.
// Phase A (grid (32,16) matches both): rope + V-transpose for (bh, s-slab).
// this_grid().sync() (agent-scope fences handle cross-XCD K/V visibility).
// Phase B: attn v9 with Q fragments loaded DIRECT from global (qs region and
// its prologue barrier deleted; each lane's qf fragment is 16 contiguous B).
// LDS 64 KB (vbuf 16KB overlays ks) -> exactly 2 blocks/CU = 512-block
// cooperative residency on 256 CUs.
// ---------------------------------------------------------------------------
#define QSCALE   0.18033688011112042f   // 0.125 * log2(e)
#define NEG12L2E -17.312340490667562f   // -12 * log2(e)

__global__ __launch_bounds__(256, 2) void ropeattn_kernel(
    const u16* __restrict__ qkv, const float* __restrict__ kp,
    u16* __restrict__ q, u16* __restrict__ k, u16* __restrict__ vt,
    u16* __restrict__ ctx)
{
    __shared__ u16 pool[32768];      // 64 KB
    u16* ks = pool;                  // K tile [key][d]        16 KB
    u16* vs = pool + 8192;           // V^T tile [d][key]      16 KB
    u16* ps = pool + 16384;          // P [q][key]             32 KB
    u32* vbuf = (u32*)pool;          // rope-phase overlay     16 KB

    const int tid  = threadIdx.x;
    const int bh   = blockIdx.x;
    const int b    = bh >> 2;
    const int h    = bh & 3;

    // ---------------- phase A: rope + V transpose for slab blockIdx.y -----
    {
        const int s0 = blockIdx.y * 128;
        const int t  = tid;
        const int dp = t & 31;             // d-pair index
        const int d  = dp * 2;

        const size_t qkbase = ((size_t)bh * S_ + s0) * DH;
#pragma unroll
        for (int i = 0; i < 16; i++) {
            const int sl = i * 8 + (t >> 5);            // 0..127
            const int s  = s0 + sl;
            const u16* src = qkv + (size_t)(b * S_ + s) * 768 + h * 192 + dp * 6;
            const u32 w0 = *(const u32*)(src);          // [q_e, k_e]
            const u32 w1 = *(const u32*)(src + 2);      // [v_e, q_o]
            const u32 w2 = *(const u32*)(src + 4);      // [k_o, v_o]
            const float qe = bf2f((u16)w0), ke = bf2f((u16)(w0 >> 16));
            const float qo = bf2f((u16)(w1 >> 16));
            const float ko = bf2f((u16)w2);

            const size_t kidx = ((size_t)b * S_ + s) * DH + d;
            const float2 cs = *(const float2*)(kp + kidx);
            const float2 sn = *(const float2*)(kp + (size_t)B_ * S_ * DH + kidx);

            const float qe2 = (qe * cs.x - qo * sn.x) * QSCALE;
            const float qo2 = (qo * cs.y + qe * sn.y) * QSCALE;
            const float ke2 = ke * cs.x - ko * sn.x;
            const float ko2 = ko * cs.y + ke * sn.y;

            const size_t oidx = qkbase + (size_t)sl * DH + d;
            *(u32*)(q + oidx) = (u32)f2bf(qe2) | ((u32)f2bf(qo2) << 16);
            *(u32*)(k + oidx) = (u32)f2bf(ke2) | ((u32)f2bf(ko2) << 16);
            vbuf[dp * 128 + (sl ^ dp)] = (w1 & 0xffffu) | (w2 & 0xffff0000u);
        }
        __syncthreads();

        u16* vtp = vt + (size_t)bh * DH * S_ + s0;
#pragma unroll
        for (int i = 0; i < 16; i++) {
            const int dd  = i * 4 + (t >> 6);           // 0..63
            const int sp  = t & 63;                     // s-pair index
            const int dpr = dd >> 1;
            const u32 a = vbuf[dpr * 128 + ((2 * sp)     ^ dpr)];   // s = 2sp
            const u32 c = vbuf[dpr * 128 + ((2 * sp + 1) ^ dpr)];   // s = 2sp+1
            const u32 o = (dd & 1) ? ((a >> 16)      | (c & 0xffff0000u))
                                   : ((a & 0xffffu)  | (c << 16));
            *(u32*)(vtp + (size_t)dd * S_ + 2 * sp) = o;
        }
    }

    cooperative_groups::this_grid().sync();   // all q/k/vt visible device-wide

    // ---------------- phase B: flash attention v9 (no qs; qf from global) --
    const int w    = tid >> 6;
    const int lane = tid & 63;
    const int n    = lane & 15;
    const int quad = lane >> 4;
    const int lrow = lane >> 3;          // 0..7   (K staging row)
    const int vrow = lane >> 4;          // 0..3   (V staging row)
    const int q0   = blockIdx.y * 128;
    const int nsw  = n & 7;              // swizzle key for fragment reads

    const int kcol  = (((lane & 7) ^ lrow) * 8);            // K: row&7 == lrow
    const int vcol0 = (((lane & 15) ^ vrow) * 8);           // V, it even
    const int vcol1 = (((lane & 15) ^ (4 + vrow)) * 8);     // V, it odd

    const u16* qbase = q  + (size_t)bh * S_ * DH;
    const u16* kbase = k  + (size_t)bh * S_ * DH;
    const u16* vbase = vt + (size_t)bh * DH * S_;

    // Q fragments direct from global: lane (n,quad), rows w*32+mb*16+n,
    // 16B at d-offset (t*4+quad)*8
    bf16x8 qf[2][2];
#pragma unroll
    for (int mb = 0; mb < 2; mb++)
#pragma unroll
        for (int t = 0; t < 2; t++)
            qf[mb][t] = *(const bf16x8*)(qbase +
                (size_t)(q0 + w * 32 + mb * 16 + n) * DH + (t * 4 + quad) * 8);

    f32x4 o[2][4];
#pragma unroll
    for (int mb = 0; mb < 2; mb++)
#pragma unroll
        for (int j = 0; j < 4; j++) o[mb][j] = (f32x4){0.f, 0.f, 0.f, 0.f};
    float lrun[2] = {0.f, 0.f};          // lane-local row-sum partials (q = mb*16+n)

    for (int kb = 0; kb < S_ / 128; kb++) {
        const int k0 = kb * 128;
        __syncthreads();   // all prior-tile reads of ks/vs done
#pragma unroll
        for (int it = 0; it < 4; it++) {
            const int r0 = w * 32 + it * 8;      // wave-uniform K rows (==0 mod 8)
            gload16(kbase + (size_t)(k0 + r0 + lrow) * DH + kcol, &ks[r0 * 64]);
            const int d0 = w * 16 + it * 4;      // wave-uniform V^T rows
            gload16(vbase + (size_t)(d0 + vrow) * S_ + k0 + ((it & 1) ? vcol1 : vcol0),
                    &vs[d0 * 128]);
        }
        __syncthreads();   // DMA drained

        // QK^T swapped: sacc[mb][j][r] = S2[key=16j+4quad+r][q=mb*16+n] - 12*log2e
        f32x4 sacc[2][8];
#pragma unroll
        for (int mb = 0; mb < 2; mb++)
#pragma unroll
            for (int j = 0; j < 8; j++)
                sacc[mb][j] = (f32x4){NEG12L2E, NEG12L2E, NEG12L2E, NEG12L2E};
        __builtin_amdgcn_s_setprio(1);
#pragma unroll
        for (int t = 0; t < 2; t++) {
#pragma unroll
            for (int j = 0; j < 8; j++) {
                const bf16x8 kf = *(const bf16x8*)
                    &ks[(16 * j + n) * 64 + (((t * 4 + quad) ^ nsw) * 8)];
                sacc[0][j] = __builtin_amdgcn_mfma_f32_16x16x32_bf16(kf, qf[0][t], sacc[0][j], 0, 0, 0);
                sacc[1][j] = __builtin_amdgcn_mfma_f32_16x16x32_bf16(kf, qf[1][t], sacc[1][j], 0, 0, 0);
            }
        }
        __builtin_amdgcn_s_setprio(0);
        // no barrier: ps is a dedicated region, own-rows only

        // softmax: exp2, pack 4 consecutive keys -> one 8B LDS store
#pragma unroll
        for (int mb = 0; mb < 2; mb++) {
            float rs = 0.f;
            const int prow = (w * 32 + mb * 16 + n) * 128;   // row&7 == n&7
#pragma unroll
            for (int j = 0; j < 8; j++) {
                const float e0 = __builtin_amdgcn_exp2f(sacc[mb][j][0]);
                const float e1 = __builtin_amdgcn_exp2f(sacc[mb][j][1]);
                const float e2 = __builtin_amdgcn_exp2f(sacc[mb][j][2]);
                const float e3 = __builtin_amdgcn_exp2f(sacc[mb][j][3]);
                rs += (e0 + e1) + (e2 + e3);
                uint2 pk;
                pk.x = (u32)f2bf(e0) | ((u32)f2bf(e1) << 16);
                pk.y = (u32)f2bf(e2) | ((u32)f2bf(e3) << 16);
                const int blk = (4 * j + quad) ^ (nsw << 2);   // 8B-block swizzle
                *(uint2*)&ps[prow + blk * 4] = pk;
            }
            lrun[mb] += rs;
        }

        // PV: pf = A-operand read of own q-rows (swizzle matches write)
        __builtin_amdgcn_s_setprio(1);
#pragma unroll
        for (int kt = 0; kt < 4; kt++) {
            const bf16x8 pf0 = *(const bf16x8*)
                &ps[(w * 32 +      n) * 128 + ((32 * kt + 8 * quad) ^ (nsw << 4))];
            const bf16x8 pf1 = *(const bf16x8*)
                &ps[(w * 32 + 16 + n) * 128 + ((32 * kt + 8 * quad) ^ (nsw << 4))];
#pragma unroll
            for (int nt = 0; nt < 4; nt++) {
                const bf16x8 vf = *(const bf16x8*)
                    &vs[(16 * nt + n) * 128 + (((kt * 4 + quad) ^ nsw) * 8)];
                o[0][nt] = __builtin_amdgcn_mfma_f32_16x16x32_bf16(pf0, vf, o[0][nt], 0, 0, 0);
                o[1][nt] = __builtin_amdgcn_mfma_f32_16x16x32_bf16(pf1, vf, o[1][nt], 0, 0, 0);
            }
        }
        __builtin_amdgcn_s_setprio(0);
    }

    // epilogue: reduce lane-partials across the 4 quads (lanes n, n+16, n+32, n+48)
#pragma unroll
    for (int mb = 0; mb < 2; mb++) {
        float s = lrun[mb];
        s += __shfl_xor(s, 16);
        s += __shfl_xor(s, 32);
        lrun[mb] = s;
    }

    // output: o[mb][nt][r] = ctx[q = mb*16+quad*4+r][d = 16nt+n]
#pragma unroll
    for (int mb = 0; mb < 2; mb++) {
#pragma unroll
        for (int r = 0; r < 4; r++) {
            const float sv = __shfl(lrun[mb], quad * 4 + r);
            const float inv = 1.f / sv;
            const int row = q0 + w * 32 + mb * 16 + quad * 4 + r;
#pragma unroll
            for (int nt = 0; nt < 4; nt++)
                ctx[((size_t)b * S_ + row) * D_ + h * DH + 16 * nt + n] = f2bf(o[mb][nt][r] * inv);
        }
    }
}

// ---------------------------------------------------------------------------
// LayerNorm + exact GELU, wave-per-row: wave w owns row bid*4+w; lane holds
// 8 consecutive elems (uint4); pure shfl reduce — no LDS, no barriers.
// ---------------------------------------------------------------------------
__global__ __launch_bounds__(256) void ln_gelu_kernel(
    const u16* __restrict__ x, const float* __restrict__ g,
    const float* __restrict__ bt, u16* __restrict__ y)
{
    const int m    = blockIdx.x * 4 + (threadIdx.x >> 6);
    const int lane = threadIdx.x & 63;
    const int c0   = lane * 8;
    uint4 xv = *(const uint4*)(x + (size_t)m * 512 + c0);
    const u16* xp = (const u16*)&xv;
    float v[8];
    float s = 0.f, sq = 0.f;
#pragma unroll
    for (int j = 0; j < 8; j++) {
        v[j] = bf2f(xp[j]);
        s  += v[j];
        sq += v[j] * v[j];
    }
#pragma unroll
    for (int off = 1; off < 64; off <<= 1) {
        s  += __shfl_xor(s, off);
        sq += __shfl_xor(sq, off);
    }
    const float mu   = s * (1.f / 512.f);
    const float var  = sq * (1.f / 512.f) - mu * mu;
    const float rstd = rsqrtf(var + 1e-5f);

    const float4 g0 = *(const float4*)(g  + c0);
    const float4 g1 = *(const float4*)(g  + c0 + 4);
    const float4 b0 = *(const float4*)(bt + c0);
    const float4 b1 = *(const float4*)(bt + c0 + 4);
    const float gg[8] = {g0.x, g0.y, g0.z, g0.w, g1.x, g1.y, g1.z, g1.w};
    const float bb[8] = {b0.x, b0.y, b0.z, b0.w, b1.x, b1.y, b1.z, b1.w};
    u16 o[8];
#pragma unroll
    for (int j = 0; j < 8; j++) {
        const float yj = (v[j] - mu) * rstd * gg[j] + bb[j];
        o[j] = f2bf(0.5f * yj * (1.f + erff(yj * 0.70710678118654752f)));
    }
    *(uint4*)(y + (size_t)m * 512 + c0) = *(const uint4*)o;
}

// ---------------------------------------------------------------------------
extern "C" void kernel_launch(void* const* d_in, const int* in_sizes, int n_in,
                              void* d_out, int out_size, void* d_ws, size_t ws_size,
                              hipStream_t stream)
{
    const float* desc   = (const float*)d_in[0];
    const float* kp     = (const float*)d_in[1];
    const float* Wqkv_w = (const float*)d_in[2];
    const float* Wqkv_b = (const float*)d_in[3];
    const float* Wo_w   = (const float*)d_in[4];
    const float* Wo_b   = (const float*)d_in[5];
    const float* W1_w   = (const float*)d_in[6];
    const float* W1_b   = (const float*)d_in[7];
    const float* ln_g   = (const float*)d_in[8];
    const float* ln_b   = (const float*)d_in[9];
    const float* W2_w   = (const float*)d_in[10];
    const float* W2_b   = (const float*)d_in[11];
    float* out = (float*)d_out;
    float* ws  = (float*)d_ws;

    // workspace (float units; QS=4.19M).
    u16*   qkvb  = (u16*)ws;
    u16*   x1b   = (u16*)(ws + 2 * (size_t)QS);
    u16*   qb    = (u16*)(ws + 3 * (size_t)QS);
    u16*   kb    = (u16*)(ws + (size_t)(3.5 * QS));
    u16*   x1g   = qb;                            // reuse q/k space after attn
    u16*   ctxb  = (u16*)(ws + (size_t)(4.5 * QS));
    u16*   descb = (u16*)(ws + 5 * (size_t)QS);
    float* bias1f = ws + (size_t)(5.5 * QS);      // 512 floats
    u16*   wpool = (u16*)(ws + 6 * (size_t)QS);
    u16*   vtb   = (u16*)(ws + (size_t)(6.5 * QS));
    u16* wqkvb = wpool;                       // 768*256 = 196608
    u16* w2b   = wqkvb + 196608;              // 256*512 = 131072
    u16* w1f   = w2b   + 131072;              // 512*512 = 262144 (fused W1')

    const dim3 blk(256);

    // 0) casts + W1 split + bias' fold + Wfused — one launch
    cast7_kernel<<<dim3(5696), blk, 0, stream>>>(
        desc, descb, Wqkv_w, wqkvb, Wo_w, W1_w, w1f, W2_w, w2b,
        W1_b, Wo_b, bias1f);

    // 1) QKV projection -> bf16 qkvb [M,768]
    gemm_bf16<4, 0, 0, 1><<<dim3(M_ / 128, 768 / 128), blk, 0, stream>>>(
        descb, nullptr, wqkvb, Wqkv_b, nullptr, nullptr, qkvb, 256, 768, 768);

    // 2+3) cooperative fused rope + V-transpose + flash attention
    {
        const u16* a0 = qkvb; const float* a1 = kp;
        u16* a2 = qb; u16* a3 = kb; u16* a4 = vtb; u16* a5 = ctxb;
        void* args[] = {(void*)&a0, (void*)&a1, (void*)&a2,
                        (void*)&a3, (void*)&a4, (void*)&a5};
        hipLaunchCooperativeKernel((void*)ropeattn_kernel,
                                   dim3(B_ * H_, S_ / 128), blk, args, 0, stream);
    }

    // 4) W1' on concat(descb, ctxb) -> bf16 x1b [M,512]   (Wo folded in)
    gemm_bf16<4, 1, 0, 1><<<dim3(M_ / 128, 512 / 128), blk, 0, stream>>>(
        descb, ctxb, w1f, bias1f, nullptr, nullptr, x1b, 512, 512, 512);

    // 5) LayerNorm + GELU (wave-per-row): bf16 in -> bf16 x1g
    ln_gelu_kernel<<<dim3(M_ / 4), blk, 0, stream>>>(x1b, ln_g, ln_b, x1g);

    // 6) W2 + bias + residual -> out fp32
    gemm_bf16<2, 0, 1, 0><<<dim3(M_ / 128, 256 / 64), blk, 0, stream>>>(
        x1g, nullptr, w2b, W2_b, desc, out, nullptr, 512, 256, 256);
}

// Round 16
// 238.617 us; speedup vs baseline: 1.3459x; 1.3459x over previous
//
#include <hip/hip_runtime.h>
#include <math.h>

#define B_  8
#define S_  2048
#define D_  256
#define H_  4
#define DH  64
#define M_  (B_ * S_)          // 16384 rows
#define QS  4194304            // M_ * D_ elements

typedef __attribute__((ext_vector_type(8))) short bf16x8;   // 8 bf16 = 4 VGPRs
typedef __attribute__((ext_vector_type(4))) float f32x4;
typedef unsigned short u16;
typedef unsigned int   u32;

#define AS1 __attribute__((address_space(1)))
#define AS3 __attribute__((address_space(3)))

__device__ __forceinline__ u16 f2bf(float x) {
    union { float f; u32 u; } c; c.f = x;
    u32 r = (c.u + 0x7fffu + ((c.u >> 16) & 1u)) >> 16;   // RNE
    return (u16)r;
}
__device__ __forceinline__ float bf2f(u16 x) {
    union { u32 u; float f; } c; c.u = ((u32)x) << 16;
    return c.f;
}

// async global->LDS, 16B per lane; LDS dest = wave-uniform base + lane*16
__device__ __forceinline__ void gload16(const void* g, void* l) {
    __builtin_amdgcn_global_load_lds((const AS1 unsigned int*)g,
                                     (AS3 unsigned int*)l, 16, 0, 0);
}

// ---------------------------------------------------------------------------
// cast7: casts + W1 split + bias' fold + Wfused — ALL setup in ONE launch.
// Block ranges:
//   [0,4096)     desc cast
//   [4096,4288)  Wqkv cast
//   [4288,4544)  W1 cast (LEFT half -> w1f cols<256)
//   [4544,4672)  W2 cast
//   [4672,5184)  bias' fold: block n -> bias1f[n] = W1b[n]·Wo_b + W1_b[n]
//   [5184,5696)  Wfused: block row -> w1f[row][256+col] = W1b[row]·Wo[:,col]
// ---------------------------------------------------------------------------
__global__ __launch_bounds__(256) void cast7_kernel(
    const float* __restrict__ desc, u16* __restrict__ descb,
    const float* __restrict__ wqkv, u16* __restrict__ wqkvb,
    const float* __restrict__ wo,   const float* __restrict__ w1,
    u16* __restrict__ w1f,
    const float* __restrict__ w2,   u16* __restrict__ w2b,
    const float* __restrict__ w1_b, const float* __restrict__ wo_b,
    float* __restrict__ bias1f)
{
    int bid = blockIdx.x;
    const int tid = threadIdx.x;

    if (bid >= 5184) {          // Wfused: row = bid-5184, col = tid
        const int row = bid - 5184;
        const int col = tid;
        const float* wrow = w1 + (size_t)row * 512 + 256;   // uniform scalar reads
        float acc = 0.f;
#pragma unroll 4
        for (int k = 0; k < 256; k++)
            acc += wrow[k] * wo[(size_t)k * 256 + col];     // Wo coalesced, L2-hot
        w1f[(size_t)row * 512 + 256 + col] = f2bf(acc);
        return;
    }
    if (bid >= 4672) {          // bias' fold: block n, coalesced 256-dot
        __shared__ float red[4];
        const int n = bid - 4672;
        float p = w1[(size_t)n * 512 + 256 + tid] * wo_b[tid];
#pragma unroll
        for (int off = 1; off < 64; off <<= 1) p += __shfl_xor(p, off);
        if ((tid & 63) == 0) red[tid >> 6] = p;
        __syncthreads();
        if (tid == 0) bias1f[n] = red[0] + red[1] + red[2] + red[3] + w1_b[n];
        return;
    }
    if (bid >= 4544) {          // W2 cast
        const int i = ((bid - 4544) * 256 + tid) * 4;
        const float4 v = *(const float4*)(w2 + i);
        u16 o[4] = {f2bf(v.x), f2bf(v.y), f2bf(v.z), f2bf(v.w)};
        *(uint2*)(w2b + i) = *(const uint2*)o;
        return;
    }
    if (bid >= 4288) {          // W1 cast: LEFT half only -> w1f cols<256
        const int e = ((bid - 4288) * 256 + tid) * 4;
        const int row = e >> 9, col = e & 511;
        if (col < 256) {
            const float4 v = *(const float4*)(w1 + e);
            u16 o[4] = {f2bf(v.x), f2bf(v.y), f2bf(v.z), f2bf(v.w)};
            *(uint2*)(w1f + (size_t)row * 512 + col) = *(const uint2*)o;
        }
        return;
    }
    // desc or Wqkv
    const float* s; u16* d;
    if (bid < 4096) { s = desc; d = descb; }
    else            { s = wqkv; d = wqkvb; bid -= 4096; }
    const int i = (bid * 256 + tid) * 4;
    const float4 v = *(const float4*)(s + i);
    u16 o[4] = {f2bf(v.x), f2bf(v.y), f2bf(v.z), f2bf(v.w)};
    *(uint2*)(d + i) = *(const uint2*)o;
}

// ---------------------------------------------------------------------------
// bf16 MFMA GEMM (m97 structure): C = A*W^T + bias.
// Tile 128 x (NT*32), BK=64, 256 thr (4 waves, 2x2 wave grid). 2D grid.
// ---------------------------------------------------------------------------
template <int NT, int CONCAT, int RES, int OUTBF16>
__global__ __launch_bounds__(256) void gemm_bf16(
    const u16* __restrict__ A, const u16* __restrict__ A2,
    const u16* __restrict__ W, const float* __restrict__ bias,
    const float* __restrict__ res, float* __restrict__ Cf,
    u16* __restrict__ Cb, int K, int N, int ldc)
{
    __shared__ u16 As[128 * 64];
    __shared__ u16 Bs[NT * 32 * 64];
    const int tid  = threadIdx.x;
    const int w    = tid >> 6;
    const int lane = tid & 63;
    const int n    = lane & 15;
    const int quad = lane >> 4;
    const int m0   = blockIdx.x * 128;
    const int n0   = blockIdx.y * (NT * 32);
    const int m_off = (w >> 1) * 64;
    const int n_off = (w & 1) * (NT * 16);
    const int lrow = lane >> 3;          // 0..7
    const int lcol = (lane & 7) * 8;     // bf16 elem offset

    f32x4 acc[4][NT];
#pragma unroll
    for (int i = 0; i < 4; i++)
#pragma unroll
        for (int j = 0; j < NT; j++) acc[i][j] = (f32x4){0.f, 0.f, 0.f, 0.f};

    for (int k0 = 0; k0 < K; k0 += 64) {
        const u16* Asrc;
        int kb, lda;
        if (CONCAT) { Asrc = (k0 < 256) ? A : A2; kb = k0 & 255; lda = 256; }
        else        { Asrc = A; kb = k0; lda = K; }

        __syncthreads();
#pragma unroll
        for (int it = 0; it < 4; it++) {
            const int r0 = it * 32 + w * 8;      // wave-uniform
            gload16(Asrc + (size_t)(m0 + r0 + lrow) * lda + kb + lcol, &As[r0 * 64]);
        }
#pragma unroll
        for (int it = 0; it < NT; it++) {
            const int r0 = it * 32 + w * 8;
            gload16(W + (size_t)(n0 + r0 + lrow) * K + k0 + lcol, &Bs[r0 * 64]);
        }
        __syncthreads();

        bf16x8 af[4][2], bf[NT][2];
#pragma unroll
        for (int mt = 0; mt < 4; mt++)
#pragma unroll
            for (int t = 0; t < 2; t++)
                af[mt][t] = *(const bf16x8*)&As[(m_off + mt * 16 + n) * 64 + t * 32 + quad * 8];
#pragma unroll
        for (int nt = 0; nt < NT; nt++)
#pragma unroll
            for (int t = 0; t < 2; t++)
                bf[nt][t] = *(const bf16x8*)&Bs[(n_off + nt * 16 + n) * 64 + t * 32 + quad * 8];

#pragma unroll
        for (int mt = 0; mt < 4; mt++)
#pragma unroll
            for (int nt = 0; nt < NT; nt++) {
                acc[mt][nt] = __builtin_amdgcn_mfma_f32_16x16x32_bf16(af[mt][0], bf[nt][0], acc[mt][nt], 0, 0, 0);
                acc[mt][nt] = __builtin_amdgcn_mfma_f32_16x16x32_bf16(af[mt][1], bf[nt][1], acc[mt][nt], 0, 0, 0);
            }
    }

#pragma unroll
    for (int nt = 0; nt < NT; nt++) {
        const int col = n0 + n_off + nt * 16 + n;
        const float bv = bias[col];
#pragma unroll
        for (int mt = 0; mt < 4; mt++) {
#pragma unroll
            for (int r = 0; r < 4; r++) {
                const int row = m0 + m_off + mt * 16 + quad * 4 + r;
                float o = acc[mt][nt][r] + bv;
                if (RES) o += res[(size_t)row * ldc + col];
                if (OUTBF16) Cb[(size_t)row * ldc + col] = f2bf(o);
                else         Cf[(size_t)row * ldc + col] = o;
            }
        }
    }
}

// ---------------------------------------------------------------------------
// ropevt: fused rope + V transpose. Block = (bh, 128-row s-slab), 256 thr.
// Rope math identical to rope v3 (q pre-scaled by 0.125*log2e). V pairs go
// to LDS vbuf[dp][sl^dp] (XOR -> conflict-free writes), then a coalesced
// u32 writeback emits vt[bh][d][s].
// ---------------------------------------------------------------------------
#define QSCALE 0.18033688011112042f    // 0.125 * log2(e)

__global__ __launch_bounds__(256) void ropevt_kernel(
    const u16* __restrict__ qkv, const float* __restrict__ kp,
    u16* __restrict__ q, u16* __restrict__ k, u16* __restrict__ vt)
{
    __shared__ u32 vbuf[32 * 128];     // [dp][sl ^ dp], 16 KB

    const int bh = blockIdx.x;
    const int s0 = blockIdx.y * 128;
    const int b  = bh >> 2;
    const int h  = bh & 3;
    const int t  = threadIdx.x;
    const int dp = t & 31;             // d-pair index
    const int d  = dp * 2;

    const size_t qkbase = ((size_t)bh * S_ + s0) * DH;
#pragma unroll
    for (int i = 0; i < 16; i++) {
        const int sl = i * 8 + (t >> 5);            // 0..127
        const int s  = s0 + sl;
        const u16* src = qkv + (size_t)(b * S_ + s) * 768 + h * 192 + dp * 6;
        const u32 w0 = *(const u32*)(src);          // [q_e, k_e]
        const u32 w1 = *(const u32*)(src + 2);      // [v_e, q_o]
        const u32 w2 = *(const u32*)(src + 4);      // [k_o, v_o]
        const float qe = bf2f((u16)w0), ke = bf2f((u16)(w0 >> 16));
        const float qo = bf2f((u16)(w1 >> 16));
        const float ko = bf2f((u16)w2);

        const size_t kidx = ((size_t)b * S_ + s) * DH + d;
        const float2 cs = *(const float2*)(kp + kidx);
        const float2 sn = *(const float2*)(kp + (size_t)B_ * S_ * DH + kidx);

        const float qe2 = (qe * cs.x - qo * sn.x) * QSCALE;
        const float qo2 = (qo * cs.y + qe * sn.y) * QSCALE;
        const float ke2 = ke * cs.x - ko * sn.x;
        const float ko2 = ko * cs.y + ke * sn.y;

        const size_t oidx = qkbase + (size_t)sl * DH + d;
        *(u32*)(q + oidx) = (u32)f2bf(qe2) | ((u32)f2bf(qo2) << 16);
        *(u32*)(k + oidx) = (u32)f2bf(ke2) | ((u32)f2bf(ko2) << 16);
        vbuf[dp * 128 + (sl ^ dp)] = (w1 & 0xffffu) | (w2 & 0xffff0000u);
    }
    __syncthreads();

    // writeback: vt[bh][dd][s0 + 2sp .. +1], one u32 per thread-item
    u16* vtp = vt + (size_t)bh * DH * S_ + s0;
#pragma unroll
    for (int i = 0; i < 16; i++) {
        const int dd  = i * 4 + (t >> 6);           // 0..63
        const int sp  = t & 63;                     // s-pair index
        const int dpr = dd >> 1;
        const u32 a = vbuf[dpr * 128 + ((2 * sp)     ^ dpr)];   // s = 2sp
        const u32 c = vbuf[dpr * 128 + ((2 * sp + 1) ^ dpr)];   // s = 2sp+1
        const u32 o = (dd & 1) ? ((a >> 16)      | (c & 0xffff0000u))
                               : ((a & 0xffffu)  | (c << 16));
        *(u32*)(vtp + (size_t)dd * S_ + 2 * sp) = o;
    }
}

// ---------------------------------------------------------------------------
// Flash attention v10 = v9 with qs region REMOVED: Q fragments loaded direct
// from global (indexing verified in round 14's fused kernel). LDS 64 KB.
// ---------------------------------------------------------------------------
#define NEG12L2E -17.312340490667562f   // -12 * log2(e)

__global__ __launch_bounds__(256, 2) void attn_kernel(
    const u16* __restrict__ q, const u16* __restrict__ k,
    const u16* __restrict__ vt, u16* __restrict__ ctx)
{
    __shared__ u16 ks[128 * 64];     // K tile [key][d]          16 KB
    __shared__ u16 vs[64 * 128];     // V^T tile [d][key]        16 KB
    __shared__ u16 ps[128 * 128];    // P [q][key]               32 KB

    const int tid  = threadIdx.x;
    const int w    = tid >> 6;
    const int lane = tid & 63;
    const int n    = lane & 15;
    const int quad = lane >> 4;
    const int lrow = lane >> 3;          // 0..7   (K staging row)
    const int vrow = lane >> 4;          // 0..3   (V staging row)
    const int bh   = blockIdx.x;
    const int q0   = blockIdx.y * 128;
    const int nsw  = n & 7;              // swizzle key for fragment reads

    const int kcol  = (((lane & 7) ^ lrow) * 8);            // K: row&7 == lrow
    const int vcol0 = (((lane & 15) ^ vrow) * 8);           // V, it even
    const int vcol1 = (((lane & 15) ^ (4 + vrow)) * 8);     // V, it odd

    const u16* qbase = q  + (size_t)bh * S_ * DH;
    const u16* kbase = k  + (size_t)bh * S_ * DH;
    const u16* vbase = vt + (size_t)bh * DH * S_;
    const int b    = bh >> 2;
    const int h    = bh & 3;

    // Q fragments direct from global (no LDS staging): lane (n,quad),
    // rows w*32+mb*16+n, 16B at d-offset (t*4+quad)*8.
    bf16x8 qf[2][2];
#pragma unroll
    for (int mb = 0; mb < 2; mb++)
#pragma unroll
        for (int t = 0; t < 2; t++)
            qf[mb][t] = *(const bf16x8*)(qbase +
                (size_t)(q0 + w * 32 + mb * 16 + n) * DH + (t * 4 + quad) * 8);

    f32x4 o[2][4];
#pragma unroll
    for (int mb = 0; mb < 2; mb++)
#pragma unroll
        for (int j = 0; j < 4; j++) o[mb][j] = (f32x4){0.f, 0.f, 0.f, 0.f};
    float lrun[2] = {0.f, 0.f};          // lane-local row-sum partials (q = mb*16+n)

    for (int kb = 0; kb < S_ / 128; kb++) {
        const int k0 = kb * 128;
        __syncthreads();   // all prior-tile reads of ks/vs done
#pragma unroll
        for (int it = 0; it < 4; it++) {
            const int r0 = w * 32 + it * 8;      // wave-uniform K rows (==0 mod 8)
            gload16(kbase + (size_t)(k0 + r0 + lrow) * DH + kcol, &ks[r0 * 64]);
            const int d0 = w * 16 + it * 4;      // wave-uniform V^T rows
            gload16(vbase + (size_t)(d0 + vrow) * S_ + k0 + ((it & 1) ? vcol1 : vcol0),
                    &vs[d0 * 128]);
        }
        __syncthreads();   // DMA drained

        // QK^T swapped: sacc[mb][j][r] = S2[key=16j+4quad+r][q=mb*16+n] - 12*log2e
        f32x4 sacc[2][8];
#pragma unroll
        for (int mb = 0; mb < 2; mb++)
#pragma unroll
            for (int j = 0; j < 8; j++)
                sacc[mb][j] = (f32x4){NEG12L2E, NEG12L2E, NEG12L2E, NEG12L2E};
        __builtin_amdgcn_s_setprio(1);
#pragma unroll
        for (int t = 0; t < 2; t++) {
#pragma unroll
            for (int j = 0; j < 8; j++) {
                const bf16x8 kf = *(const bf16x8*)
                    &ks[(16 * j + n) * 64 + (((t * 4 + quad) ^ nsw) * 8)];
                sacc[0][j] = __builtin_amdgcn_mfma_f32_16x16x32_bf16(kf, qf[0][t], sacc[0][j], 0, 0, 0);
                sacc[1][j] = __builtin_amdgcn_mfma_f32_16x16x32_bf16(kf, qf[1][t], sacc[1][j], 0, 0, 0);
            }
        }
        __builtin_amdgcn_s_setprio(0);
        // no barrier: ps is a dedicated region, own-rows only

        // softmax: exp2, pack 4 consecutive keys -> one 8B LDS store
#pragma unroll
        for (int mb = 0; mb < 2; mb++) {
            float rs = 0.f;
            const int prow = (w * 32 + mb * 16 + n) * 128;   // row&7 == n&7
#pragma unroll
            for (int j = 0; j < 8; j++) {
                const float e0 = __builtin_amdgcn_exp2f(sacc[mb][j][0]);
                const float e1 = __builtin_amdgcn_exp2f(sacc[mb][j][1]);
                const float e2 = __builtin_amdgcn_exp2f(sacc[mb][j][2]);
                const float e3 = __builtin_amdgcn_exp2f(sacc[mb][j][3]);
                rs += (e0 + e1) + (e2 + e3);
                uint2 pk;
                pk.x = (u32)f2bf(e0) | ((u32)f2bf(e1) << 16);
                pk.y = (u32)f2bf(e2) | ((u32)f2bf(e3) << 16);
                const int blk = (4 * j + quad) ^ (nsw << 2);   // 8B-block swizzle
                *(uint2*)&ps[prow + blk * 4] = pk;
            }
            lrun[mb] += rs;
        }

        // PV: pf = A-operand read of own q-rows (swizzle matches write)
        __builtin_amdgcn_s_setprio(1);
#pragma unroll
        for (int kt = 0; kt < 4; kt++) {
            const bf16x8 pf0 = *(const bf16x8*)
                &ps[(w * 32 +      n) * 128 + ((32 * kt + 8 * quad) ^ (nsw << 4))];
            const bf16x8 pf1 = *(const bf16x8*)
                &ps[(w * 32 + 16 + n) * 128 + ((32 * kt + 8 * quad) ^ (nsw << 4))];
#pragma unroll
            for (int nt = 0; nt < 4; nt++) {
                const bf16x8 vf = *(const bf16x8*)
                    &vs[(16 * nt + n) * 128 + (((kt * 4 + quad) ^ nsw) * 8)];
                o[0][nt] = __builtin_amdgcn_mfma_f32_16x16x32_bf16(pf0, vf, o[0][nt], 0, 0, 0);
                o[1][nt] = __builtin_amdgcn_mfma_f32_16x16x32_bf16(pf1, vf, o[1][nt], 0, 0, 0);
            }
        }
        __builtin_amdgcn_s_setprio(0);
    }

    // epilogue: reduce lane-partials across the 4 quads (lanes n, n+16, n+32, n+48)
#pragma unroll
    for (int mb = 0; mb < 2; mb++) {
        float s = lrun[mb];
        s += __shfl_xor(s, 16);
        s += __shfl_xor(s, 32);
        lrun[mb] = s;
    }

    // output: o[mb][nt][r] = ctx[q = mb*16+quad*4+r][d = 16nt+n]
#pragma unroll
    for (int mb = 0; mb < 2; mb++) {
#pragma unroll
        for (int r = 0; r < 4; r++) {
            const float sv = __shfl(lrun[mb], quad * 4 + r);
            const float inv = 1.f / sv;
            const int row = q0 + w * 32 + mb * 16 + quad * 4 + r;
#pragma unroll
            for (int nt = 0; nt < 4; nt++)
                ctx[((size_t)b * S_ + row) * D_ + h * DH + 16 * nt + n] = f2bf(o[mb][nt][r] * inv);
        }
    }
}

// ---------------------------------------------------------------------------
// LayerNorm + exact GELU, wave-per-row: wave w owns row bid*4+w; lane holds
// 8 consecutive elems (uint4); pure shfl reduce — no LDS, no barriers.
// ---------------------------------------------------------------------------
__global__ __launch_bounds__(256) void ln_gelu_kernel(
    const u16* __restrict__ x, const float* __restrict__ g,
    const float* __restrict__ bt, u16* __restrict__ y)
{
    const int m    = blockIdx.x * 4 + (threadIdx.x >> 6);
    const int lane = threadIdx.x & 63;
    const int c0   = lane * 8;
    uint4 xv = *(const uint4*)(x + (size_t)m * 512 + c0);
    const u16* xp = (const u16*)&xv;
    float v[8];
    float s = 0.f, sq = 0.f;
#pragma unroll
    for (int j = 0; j < 8; j++) {
        v[j] = bf2f(xp[j]);
        s  += v[j];
        sq += v[j] * v[j];
    }
#pragma unroll
    for (int off = 1; off < 64; off <<= 1) {
        s  += __shfl_xor(s, off);
        sq += __shfl_xor(sq, off);
    }
    const float mu   = s * (1.f / 512.f);
    const float var  = sq * (1.f / 512.f) - mu * mu;
    const float rstd = rsqrtf(var + 1e-5f);

    const float4 g0 = *(const float4*)(g  + c0);
    const float4 g1 = *(const float4*)(g  + c0 + 4);
    const float4 b0 = *(const float4*)(bt + c0);
    const float4 b1 = *(const float4*)(bt + c0 + 4);
    const float gg[8] = {g0.x, g0.y, g0.z, g0.w, g1.x, g1.y, g1.z, g1.w};
    const float bb[8] = {b0.x, b0.y, b0.z, b0.w, b1.x, b1.y, b1.z, b1.w};
    u16 o[8];
#pragma unroll
    for (int j = 0; j < 8; j++) {
        const float yj = (v[j] - mu) * rstd * gg[j] + bb[j];
        o[j] = f2bf(0.5f * yj * (1.f + erff(yj * 0.70710678118654752f)));
    }
    *(uint4*)(y + (size_t)m * 512 + c0) = *(const uint4*)o;
}

// ---------------------------------------------------------------------------
extern "C" void kernel_launch(void* const* d_in, const int* in_sizes, int n_in,
                              void* d_out, int out_size, void* d_ws, size_t ws_size,
                              hipStream_t stream)
{
    const float* desc   = (const float*)d_in[0];
    const float* kp     = (const float*)d_in[1];
    const float* Wqkv_w = (const float*)d_in[2];
    const float* Wqkv_b = (const float*)d_in[3];
    const float* Wo_w   = (const float*)d_in[4];
    const float* Wo_b   = (const float*)d_in[5];
    const float* W1_w   = (const float*)d_in[6];
    const float* W1_b   = (const float*)d_in[7];
    const float* ln_g   = (const float*)d_in[8];
    const float* ln_b   = (const float*)d_in[9];
    const float* W2_w   = (const float*)d_in[10];
    const float* W2_b   = (const float*)d_in[11];
    float* out = (float*)d_out;
    float* ws  = (float*)d_ws;

    // workspace (float units; QS=4.19M).
    u16*   qkvb  = (u16*)ws;
    u16*   x1b   = (u16*)(ws + 2 * (size_t)QS);
    u16*   qb    = (u16*)(ws + 3 * (size_t)QS);
    u16*   kb    = (u16*)(ws + (size_t)(3.5 * QS));
    u16*   x1g   = qb;                            // reuse q/k space after attn
    u16*   ctxb  = (u16*)(ws + (size_t)(4.5 * QS));
    u16*   descb = (u16*)(ws + 5 * (size_t)QS);
    float* bias1f = ws + (size_t)(5.5 * QS);      // 512 floats
    u16*   wpool = (u16*)(ws + 6 * (size_t)QS);
    u16*   vtb   = (u16*)(ws + (size_t)(6.5 * QS));
    u16* wqkvb = wpool;                       // 768*256 = 196608
    u16* w2b   = wqkvb + 196608;              // 256*512 = 131072
    u16* w1f   = w2b   + 131072;              // 512*512 = 262144 (fused W1')

    const dim3 blk(256);

    // 0) casts + W1 split + bias' fold + Wfused — one launch
    cast7_kernel<<<dim3(5696), blk, 0, stream>>>(
        desc, descb, Wqkv_w, wqkvb, Wo_w, W1_w, w1f, W2_w, w2b,
        W1_b, Wo_b, bias1f);

    // 1) QKV projection -> bf16 qkvb [M,768]
    gemm_bf16<4, 0, 0, 1><<<dim3(M_ / 128, 768 / 128), blk, 0, stream>>>(
        descb, nullptr, wqkvb, Wqkv_b, nullptr, nullptr, qkvb, 256, 768, 768);

    // 2) fused rope + V transpose -> qb, kb, vtb
    ropevt_kernel<<<dim3(B_ * H_, S_ / 128), blk, 0, stream>>>(
        qkvb, kp, qb, kb, vtb);

    // 3) flash attention v10 -> ctx bf16 [M,256]
    attn_kernel<<<dim3(B_ * H_, S_ / 128), blk, 0, stream>>>(qb, kb, vtb, ctxb);

    // 4) W1' on concat(descb, ctxb) -> bf16 x1b [M,512]   (Wo folded in)
    gemm_bf16<4, 1, 0, 1><<<dim3(M_ / 128, 512 / 128), blk, 0, stream>>>(
        descb, ctxb, w1f, bias1f, nullptr, nullptr, x1b, 512, 512, 512);

    // 5) LayerNorm + GELU (wave-per-row): bf16 in -> bf16 x1g
    ln_gelu_kernel<<<dim3(M_ / 4), blk, 0, stream>>>(x1b, ln_g, ln_b, x1g);

    // 6) W2 + bias + residual -> out fp32
    gemm_bf16<2, 0, 1, 0><<<dim3(M_ / 128, 256 / 64), blk, 0, stream>>>(
        x1g, nullptr, w2b, W2_b, desc, out, nullptr, 512, 256, 256);
}

// Round 17
// 235.174 us; speedup vs baseline: 1.3656x; 1.0146x over previous
//
#include <hip/hip_runtime.h>
#include <math.h>

#define B_  8
#define S_  2048
#define D_  256
#define H_  4
#define DH  64
#define M_  (B_ * S_)          // 16384 rows
#define QS  4194304            // M_ * D_ elements

typedef __attribute__((ext_vector_type(8))) short bf16x8;   // 8 bf16 = 4 VGPRs
typedef __attribute__((ext_vector_type(4))) float f32x4;
typedef unsigned short u16;
typedef unsigned int   u32;

#define AS1 __attribute__((address_space(1)))
#define AS3 __attribute__((address_space(3)))

__device__ __forceinline__ u16 f2bf(float x) {
    union { float f; u32 u; } c; c.f = x;
    u32 r = (c.u + 0x7fffu + ((c.u >> 16) & 1u)) >> 16;   // RNE
    return (u16)r;
}
__device__ __forceinline__ float bf2f(u16 x) {
    union { u32 u; float f; } c; c.u = ((u32)x) << 16;
    return c.f;
}

// async global->LDS, 16B per lane; LDS dest = wave-uniform base + lane*16
__device__ __forceinline__ void gload16(const void* g, void* l) {
    __builtin_amdgcn_global_load_lds((const AS1 unsigned int*)g,
                                     (AS3 unsigned int*)l, 16, 0, 0);
}

// ---------------------------------------------------------------------------
// cast7: casts + W1 split + bias' fold + Wfused — ALL setup in ONE launch.
// Block ranges:
//   [0,4096)     desc cast
//   [4096,4288)  Wqkv cast
//   [4288,4544)  W1 cast (LEFT half -> w1f cols<256)
//   [4544,4672)  W2 cast
//   [4672,5184)  bias' fold: block n -> bias1f[n] = W1b[n]·Wo_b + W1_b[n]
//   [5184,5696)  Wfused: block row -> w1f[row][256+col] = W1b[row]·Wo[:,col]
// ---------------------------------------------------------------------------
__global__ __launch_bounds__(256) void cast7_kernel(
    const float* __restrict__ desc, u16* __restrict__ descb,
    const float* __restrict__ wqkv, u16* __restrict__ wqkvb,
    const float* __restrict__ wo,   const float* __restrict__ w1,
    u16* __restrict__ w1f,
    const float* __restrict__ w2,   u16* __restrict__ w2b,
    const float* __restrict__ w1_b, const float* __restrict__ wo_b,
    float* __restrict__ bias1f)
{
    int bid = blockIdx.x;
    const int tid = threadIdx.x;

    if (bid >= 5184) {          // Wfused: row = bid-5184, col = tid
        const int row = bid - 5184;
        const int col = tid;
        const float* wrow = w1 + (size_t)row * 512 + 256;   // uniform scalar reads
        float acc = 0.f;
#pragma unroll 4
        for (int k = 0; k < 256; k++)
            acc += wrow[k] * wo[(size_t)k * 256 + col];     // Wo coalesced, L2-hot
        w1f[(size_t)row * 512 + 256 + col] = f2bf(acc);
        return;
    }
    if (bid >= 4672) {          // bias' fold: block n, coalesced 256-dot
        __shared__ float red[4];
        const int n = bid - 4672;
        float p = w1[(size_t)n * 512 + 256 + tid] * wo_b[tid];
#pragma unroll
        for (int off = 1; off < 64; off <<= 1) p += __shfl_xor(p, off);
        if ((tid & 63) == 0) red[tid >> 6] = p;
        __syncthreads();
        if (tid == 0) bias1f[n] = red[0] + red[1] + red[2] + red[3] + w1_b[n];
        return;
    }
    if (bid >= 4544) {          // W2 cast
        const int i = ((bid - 4544) * 256 + tid) * 4;
        const float4 v = *(const float4*)(w2 + i);
        u16 o[4] = {f2bf(v.x), f2bf(v.y), f2bf(v.z), f2bf(v.w)};
        *(uint2*)(w2b + i) = *(const uint2*)o;
        return;
    }
    if (bid >= 4288) {          // W1 cast: LEFT half only -> w1f cols<256
        const int e = ((bid - 4288) * 256 + tid) * 4;
        const int row = e >> 9, col = e & 511;
        if (col < 256) {
            const float4 v = *(const float4*)(w1 + e);
            u16 o[4] = {f2bf(v.x), f2bf(v.y), f2bf(v.z), f2bf(v.w)};
            *(uint2*)(w1f + (size_t)row * 512 + col) = *(const uint2*)o;
        }
        return;
    }
    // desc or Wqkv
    const float* s; u16* d;
    if (bid < 4096) { s = desc; d = descb; }
    else            { s = wqkv; d = wqkvb; bid -= 4096; }
    const int i = (bid * 256 + tid) * 4;
    const float4 v = *(const float4*)(s + i);
    u16 o[4] = {f2bf(v.x), f2bf(v.y), f2bf(v.z), f2bf(v.w)};
    *(uint2*)(d + i) = *(const uint2*)o;
}

// ---------------------------------------------------------------------------
// bf16 MFMA GEMM (m97 structure): C = A*W^T + bias.
// Tile 128 x (NT*32), BK=64, 256 thr (4 waves, 2x2 wave grid). 2D grid.
// ---------------------------------------------------------------------------
template <int NT, int CONCAT, int RES, int OUTBF16>
__global__ __launch_bounds__(256) void gemm_bf16(
    const u16* __restrict__ A, const u16* __restrict__ A2,
    const u16* __restrict__ W, const float* __restrict__ bias,
    const float* __restrict__ res, float* __restrict__ Cf,
    u16* __restrict__ Cb, int K, int N, int ldc)
{
    __shared__ u16 As[128 * 64];
    __shared__ u16 Bs[NT * 32 * 64];
    const int tid  = threadIdx.x;
    const int w    = tid >> 6;
    const int lane = tid & 63;
    const int n    = lane & 15;
    const int quad = lane >> 4;
    const int m0   = blockIdx.x * 128;
    const int n0   = blockIdx.y * (NT * 32);
    const int m_off = (w >> 1) * 64;
    const int n_off = (w & 1) * (NT * 16);
    const int lrow = lane >> 3;          // 0..7
    const int lcol = (lane & 7) * 8;     // bf16 elem offset

    f32x4 acc[4][NT];
#pragma unroll
    for (int i = 0; i < 4; i++)
#pragma unroll
        for (int j = 0; j < NT; j++) acc[i][j] = (f32x4){0.f, 0.f, 0.f, 0.f};

    for (int k0 = 0; k0 < K; k0 += 64) {
        const u16* Asrc;
        int kb, lda;
        if (CONCAT) { Asrc = (k0 < 256) ? A : A2; kb = k0 & 255; lda = 256; }
        else        { Asrc = A; kb = k0; lda = K; }

        __syncthreads();
#pragma unroll
        for (int it = 0; it < 4; it++) {
            const int r0 = it * 32 + w * 8;      // wave-uniform
            gload16(Asrc + (size_t)(m0 + r0 + lrow) * lda + kb + lcol, &As[r0 * 64]);
        }
#pragma unroll
        for (int it = 0; it < NT; it++) {
            const int r0 = it * 32 + w * 8;
            gload16(W + (size_t)(n0 + r0 + lrow) * K + k0 + lcol, &Bs[r0 * 64]);
        }
        __syncthreads();

        bf16x8 af[4][2], bf[NT][2];
#pragma unroll
        for (int mt = 0; mt < 4; mt++)
#pragma unroll
            for (int t = 0; t < 2; t++)
                af[mt][t] = *(const bf16x8*)&As[(m_off + mt * 16 + n) * 64 + t * 32 + quad * 8];
#pragma unroll
        for (int nt = 0; nt < NT; nt++)
#pragma unroll
            for (int t = 0; t < 2; t++)
                bf[nt][t] = *(const bf16x8*)&Bs[(n_off + nt * 16 + n) * 64 + t * 32 + quad * 8];

#pragma unroll
        for (int mt = 0; mt < 4; mt++)
#pragma unroll
            for (int nt = 0; nt < NT; nt++) {
                acc[mt][nt] = __builtin_amdgcn_mfma_f32_16x16x32_bf16(af[mt][0], bf[nt][0], acc[mt][nt], 0, 0, 0);
                acc[mt][nt] = __builtin_amdgcn_mfma_f32_16x16x32_bf16(af[mt][1], bf[nt][1], acc[mt][nt], 0, 0, 0);
            }
    }

#pragma unroll
    for (int nt = 0; nt < NT; nt++) {
        const int col = n0 + n_off + nt * 16 + n;
        const float bv = bias[col];
#pragma unroll
        for (int mt = 0; mt < 4; mt++) {
#pragma unroll
            for (int r = 0; r < 4; r++) {
                const int row = m0 + m_off + mt * 16 + quad * 4 + r;
                float o = acc[mt][nt][r] + bv;
                if (RES) o += res[(size_t)row * ldc + col];
                if (OUTBF16) Cb[(size_t)row * ldc + col] = f2bf(o);
                else         Cf[(size_t)row * ldc + col] = o;
            }
        }
    }
}

// ---------------------------------------------------------------------------
// ropevt: fused rope + V transpose. Block = (bh, 128-row s-slab), 256 thr.
// ---------------------------------------------------------------------------
#define QSCALE 0.18033688011112042f    // 0.125 * log2(e)

__global__ __launch_bounds__(256) void ropevt_kernel(
    const u16* __restrict__ qkv, const float* __restrict__ kp,
    u16* __restrict__ q, u16* __restrict__ k, u16* __restrict__ vt)
{
    __shared__ u32 vbuf[32 * 128];     // [dp][sl ^ dp], 16 KB

    const int bh = blockIdx.x;
    const int s0 = blockIdx.y * 128;
    const int b  = bh >> 2;
    const int h  = bh & 3;
    const int t  = threadIdx.x;
    const int dp = t & 31;             // d-pair index
    const int d  = dp * 2;

    const size_t qkbase = ((size_t)bh * S_ + s0) * DH;
#pragma unroll
    for (int i = 0; i < 16; i++) {
        const int sl = i * 8 + (t >> 5);            // 0..127
        const int s  = s0 + sl;
        const u16* src = qkv + (size_t)(b * S_ + s) * 768 + h * 192 + dp * 6;
        const u32 w0 = *(const u32*)(src);          // [q_e, k_e]
        const u32 w1 = *(const u32*)(src + 2);      // [v_e, q_o]
        const u32 w2 = *(const u32*)(src + 4);      // [k_o, v_o]
        const float qe = bf2f((u16)w0), ke = bf2f((u16)(w0 >> 16));
        const float qo = bf2f((u16)(w1 >> 16));
        const float ko = bf2f((u16)w2);

        const size_t kidx = ((size_t)b * S_ + s) * DH + d;
        const float2 cs = *(const float2*)(kp + kidx);
        const float2 sn = *(const float2*)(kp + (size_t)B_ * S_ * DH + kidx);

        const float qe2 = (qe * cs.x - qo * sn.x) * QSCALE;
        const float qo2 = (qo * cs.y + qe * sn.y) * QSCALE;
        const float ke2 = ke * cs.x - ko * sn.x;
        const float ko2 = ko * cs.y + ke * sn.y;

        const size_t oidx = qkbase + (size_t)sl * DH + d;
        *(u32*)(q + oidx) = (u32)f2bf(qe2) | ((u32)f2bf(qo2) << 16);
        *(u32*)(k + oidx) = (u32)f2bf(ke2) | ((u32)f2bf(ko2) << 16);
        vbuf[dp * 128 + (sl ^ dp)] = (w1 & 0xffffu) | (w2 & 0xffff0000u);
    }
    __syncthreads();

    // writeback: vt[bh][dd][s0 + 2sp .. +1], one u32 per thread-item
    u16* vtp = vt + (size_t)bh * DH * S_ + s0;
#pragma unroll
    for (int i = 0; i < 16; i++) {
        const int dd  = i * 4 + (t >> 6);           // 0..63
        const int sp  = t & 63;                     // s-pair index
        const int dpr = dd >> 1;
        const u32 a = vbuf[dpr * 128 + ((2 * sp)     ^ dpr)];   // s = 2sp
        const u32 c = vbuf[dpr * 128 + ((2 * sp + 1) ^ dpr)];   // s = 2sp+1
        const u32 o = (dd & 1) ? ((a >> 16)      | (c & 0xffff0000u))
                               : ((a & 0xffffu)  | (c << 16));
        *(u32*)(vtp + (size_t)dd * S_ + 2 * sp) = o;
    }
}

// ---------------------------------------------------------------------------
// Flash attention v11 = v10 + double-buffered K + counted-vmcnt pipeline:
//   - ks[2] (2x16 KB): K(kb+1) issued at tile top, waited one full tile later
//   - V(kb) issued at tile top, waited only after QK+softmax (~1000 cyc cover)
//   - raw s_barrier + inline-asm counted s_waitcnt (m201-verified pattern);
//     NO vmcnt(0) drains in the main loop
// LDS 80 KB (ks0|ks1|vs|ps) -> 2 blocks/CU. Arithmetic identical to v10.
// ---------------------------------------------------------------------------
#define NEG12L2E -17.312340490667562f   // -12 * log2(e)

__global__ __launch_bounds__(256, 2) void attn_kernel(
    const u16* __restrict__ q, const u16* __restrict__ k,
    const u16* __restrict__ vt, u16* __restrict__ ctx)
{
    __shared__ u16 pool[40960];      // 80 KB
    u16* ks0 = pool;                 // K tile, even kb         16 KB
    u16* ks1 = pool + 8192;          // K tile, odd kb          16 KB
    u16* vs  = pool + 16384;         // V^T tile [d][key]       16 KB
    u16* ps  = pool + 24576;         // P [q][key]              32 KB

    const int tid  = threadIdx.x;
    const int w    = tid >> 6;
    const int lane = tid & 63;
    const int n    = lane & 15;
    const int quad = lane >> 4;
    const int lrow = lane >> 3;          // 0..7   (K staging row)
    const int vrow = lane >> 4;          // 0..3   (V staging row)
    const int bh   = blockIdx.x;
    const int q0   = blockIdx.y * 128;
    const int nsw  = n & 7;              // swizzle key for fragment reads

    const int kcol  = (((lane & 7) ^ lrow) * 8);            // K: row&7 == lrow
    const int vcol0 = (((lane & 15) ^ vrow) * 8);           // V, it even
    const int vcol1 = (((lane & 15) ^ (4 + vrow)) * 8);     // V, it odd

    const u16* qbase = q  + (size_t)bh * S_ * DH;
    const u16* kbase = k  + (size_t)bh * S_ * DH;
    const u16* vbase = vt + (size_t)bh * DH * S_;
    const int b    = bh >> 2;
    const int h    = bh & 3;

    // Q fragments direct from global (no LDS staging)
    bf16x8 qf[2][2];
#pragma unroll
    for (int mb = 0; mb < 2; mb++)
#pragma unroll
        for (int t = 0; t < 2; t++)
            qf[mb][t] = *(const bf16x8*)(qbase +
                (size_t)(q0 + w * 32 + mb * 16 + n) * DH + (t * 4 + quad) * 8);

    // prologue: K(0) -> ks0 (stays in flight until tile 0's K-wait)
#pragma unroll
    for (int it = 0; it < 4; it++) {
        const int r0 = w * 32 + it * 8;
        gload16(kbase + (size_t)(r0 + lrow) * DH + kcol, &ks0[r0 * 64]);
    }

    f32x4 o[2][4];
#pragma unroll
    for (int mb = 0; mb < 2; mb++)
#pragma unroll
        for (int j = 0; j < 4; j++) o[mb][j] = (f32x4){0.f, 0.f, 0.f, 0.f};
    float lrun[2] = {0.f, 0.f};          // lane-local row-sum partials (q = mb*16+n)

    for (int kb = 0; kb < S_ / 128; kb++) {
        const int k0 = kb * 128;
        u16* kcur = (kb & 1) ? ks1 : ks0;
        u16* knxt = (kb & 1) ? ks0 : ks1;

        // WAR barrier: all waves done PV(kb-1) reads of vs and QK(kb-1) reads
        // of ks[nxt]. No waitcnt needed (LDS reads retire before barrier-pass;
        // pending K(kb) DMA targets kcur, disjoint from overwrite targets).
        asm volatile("" ::: "memory");
        __builtin_amdgcn_s_barrier();

        // issue V(kb) -> vs, then K(kb+1) -> knxt
#pragma unroll
        for (int it = 0; it < 4; it++) {
            const int d0 = w * 16 + it * 4;
            gload16(vbase + (size_t)(d0 + vrow) * S_ + k0 + ((it & 1) ? vcol1 : vcol0),
                    &vs[d0 * 128]);
        }
        if (kb < S_ / 128 - 1) {
#pragma unroll
            for (int it = 0; it < 4; it++) {
                const int r0 = w * 32 + it * 8;
                gload16(kbase + (size_t)(k0 + 128 + r0 + lrow) * DH + kcol,
                        &knxt[r0 * 64]);
            }
            asm volatile("s_waitcnt vmcnt(8)" ::: "memory");   // K(kb) landed
        } else {
            asm volatile("s_waitcnt vmcnt(4)" ::: "memory");   // K(kb) landed
        }
        __builtin_amdgcn_s_barrier();    // all waves' K(kb) visible

        // QK^T swapped: sacc[mb][j][r] = S2[key=16j+4quad+r][q=mb*16+n] - 12*log2e
        f32x4 sacc[2][8];
#pragma unroll
        for (int mb = 0; mb < 2; mb++)
#pragma unroll
            for (int j = 0; j < 8; j++)
                sacc[mb][j] = (f32x4){NEG12L2E, NEG12L2E, NEG12L2E, NEG12L2E};
        __builtin_amdgcn_s_setprio(1);
#pragma unroll
        for (int t = 0; t < 2; t++) {
#pragma unroll
            for (int j = 0; j < 8; j++) {
                const bf16x8 kf = *(const bf16x8*)
                    &kcur[(16 * j + n) * 64 + (((t * 4 + quad) ^ nsw) * 8)];
                sacc[0][j] = __builtin_amdgcn_mfma_f32_16x16x32_bf16(kf, qf[0][t], sacc[0][j], 0, 0, 0);
                sacc[1][j] = __builtin_amdgcn_mfma_f32_16x16x32_bf16(kf, qf[1][t], sacc[1][j], 0, 0, 0);
            }
        }
        __builtin_amdgcn_s_setprio(0);

        // softmax: exp2, pack 4 consecutive keys -> one 8B LDS store (own rows)
#pragma unroll
        for (int mb = 0; mb < 2; mb++) {
            float rs = 0.f;
            const int prow = (w * 32 + mb * 16 + n) * 128;   // row&7 == n&7
#pragma unroll
            for (int j = 0; j < 8; j++) {
                const float e0 = __builtin_amdgcn_exp2f(sacc[mb][j][0]);
                const float e1 = __builtin_amdgcn_exp2f(sacc[mb][j][1]);
                const float e2 = __builtin_amdgcn_exp2f(sacc[mb][j][2]);
                const float e3 = __builtin_amdgcn_exp2f(sacc[mb][j][3]);
                rs += (e0 + e1) + (e2 + e3);
                uint2 pk;
                pk.x = (u32)f2bf(e0) | ((u32)f2bf(e1) << 16);
                pk.y = (u32)f2bf(e2) | ((u32)f2bf(e3) << 16);
                const int blk = (4 * j + quad) ^ (nsw << 2);   // 8B-block swizzle
                *(uint2*)&ps[prow + blk * 4] = pk;
            }
            lrun[mb] += rs;
        }

        // V(kb) wait: issued at tile top, latency covered by QK+softmax
        if (kb < S_ / 128 - 1) asm volatile("s_waitcnt vmcnt(4)" ::: "memory");
        else                   asm volatile("s_waitcnt vmcnt(0)" ::: "memory");
        __builtin_amdgcn_s_barrier();    // all waves' V(kb) visible

        // PV: pf = A-operand read of own q-rows (swizzle matches write)
        __builtin_amdgcn_s_setprio(1);
#pragma unroll
        for (int kt = 0; kt < 4; kt++) {
            const bf16x8 pf0 = *(const bf16x8*)
                &ps[(w * 32 +      n) * 128 + ((32 * kt + 8 * quad) ^ (nsw << 4))];
            const bf16x8 pf1 = *(const bf16x8*)
                &ps[(w * 32 + 16 + n) * 128 + ((32 * kt + 8 * quad) ^ (nsw << 4))];
#pragma unroll
            for (int nt = 0; nt < 4; nt++) {
                const bf16x8 vf = *(const bf16x8*)
                    &vs[(16 * nt + n) * 128 + (((kt * 4 + quad) ^ nsw) * 8)];
                o[0][nt] = __builtin_amdgcn_mfma_f32_16x16x32_bf16(pf0, vf, o[0][nt], 0, 0, 0);
                o[1][nt] = __builtin_amdgcn_mfma_f32_16x16x32_bf16(pf1, vf, o[1][nt], 0, 0, 0);
            }
        }
        __builtin_amdgcn_s_setprio(0);
    }

    // epilogue: reduce lane-partials across the 4 quads (lanes n, n+16, n+32, n+48)
#pragma unroll
    for (int mb = 0; mb < 2; mb++) {
        float s = lrun[mb];
        s += __shfl_xor(s, 16);
        s += __shfl_xor(s, 32);
        lrun[mb] = s;
    }

    // output: o[mb][nt][r] = ctx[q = mb*16+quad*4+r][d = 16nt+n]
#pragma unroll
    for (int mb = 0; mb < 2; mb++) {
#pragma unroll
        for (int r = 0; r < 4; r++) {
            const float sv = __shfl(lrun[mb], quad * 4 + r);
            const float inv = 1.f / sv;
            const int row = q0 + w * 32 + mb * 16 + quad * 4 + r;
#pragma unroll
            for (int nt = 0; nt < 4; nt++)
                ctx[((size_t)b * S_ + row) * D_ + h * DH + 16 * nt + n] = f2bf(o[mb][nt][r] * inv);
        }
    }
}

// ---------------------------------------------------------------------------
// LayerNorm + exact GELU, wave-per-row: wave w owns row bid*4+w; lane holds
// 8 consecutive elems (uint4); pure shfl reduce — no LDS, no barriers.
// ---------------------------------------------------------------------------
__global__ __launch_bounds__(256) void ln_gelu_kernel(
    const u16* __restrict__ x, const float* __restrict__ g,
    const float* __restrict__ bt, u16* __restrict__ y)
{
    const int m    = blockIdx.x * 4 + (threadIdx.x >> 6);
    const int lane = threadIdx.x & 63;
    const int c0   = lane * 8;
    uint4 xv = *(const uint4*)(x + (size_t)m * 512 + c0);
    const u16* xp = (const u16*)&xv;
    float v[8];
    float s = 0.f, sq = 0.f;
#pragma unroll
    for (int j = 0; j < 8; j++) {
        v[j] = bf2f(xp[j]);
        s  += v[j];
        sq += v[j] * v[j];
    }
#pragma unroll
    for (int off = 1; off < 64; off <<= 1) {
        s  += __shfl_xor(s, off);
        sq += __shfl_xor(sq, off);
    }
    const float mu   = s * (1.f / 512.f);
    const float var  = sq * (1.f / 512.f) - mu * mu;
    const float rstd = rsqrtf(var + 1e-5f);

    const float4 g0 = *(const float4*)(g  + c0);
    const float4 g1 = *(const float4*)(g  + c0 + 4);
    const float4 b0 = *(const float4*)(bt + c0);
    const float4 b1 = *(const float4*)(bt + c0 + 4);
    const float gg[8] = {g0.x, g0.y, g0.z, g0.w, g1.x, g1.y, g1.z, g1.w};
    const float bb[8] = {b0.x, b0.y, b0.z, b0.w, b1.x, b1.y, b1.z, b1.w};
    u16 o[8];
#pragma unroll
    for (int j = 0; j < 8; j++) {
        const float yj = (v[j] - mu) * rstd * gg[j] + bb[j];
        o[j] = f2bf(0.5f * yj * (1.f + erff(yj * 0.70710678118654752f)));
    }
    *(uint4*)(y + (size_t)m * 512 + c0) = *(const uint4*)o;
}

// ---------------------------------------------------------------------------
extern "C" void kernel_launch(void* const* d_in, const int* in_sizes, int n_in,
                              void* d_out, int out_size, void* d_ws, size_t ws_size,
                              hipStream_t stream)
{
    const float* desc   = (const float*)d_in[0];
    const float* kp     = (const float*)d_in[1];
    const float* Wqkv_w = (const float*)d_in[2];
    const float* Wqkv_b = (const float*)d_in[3];
    const float* Wo_w   = (const float*)d_in[4];
    const float* Wo_b   = (const float*)d_in[5];
    const float* W1_w   = (const float*)d_in[6];
    const float* W1_b   = (const float*)d_in[7];
    const float* ln_g   = (const float*)d_in[8];
    const float* ln_b   = (const float*)d_in[9];
    const float* W2_w   = (const float*)d_in[10];
    const float* W2_b   = (const float*)d_in[11];
    float* out = (float*)d_out;
    float* ws  = (float*)d_ws;

    // workspace (float units; QS=4.19M).
    u16*   qkvb  = (u16*)ws;
    u16*   x1b   = (u16*)(ws + 2 * (size_t)QS);
    u16*   qb    = (u16*)(ws + 3 * (size_t)QS);
    u16*   kb    = (u16*)(ws + (size_t)(3.5 * QS));
    u16*   x1g   = qb;                            // reuse q/k space after attn
    u16*   ctxb  = (u16*)(ws + (size_t)(4.5 * QS));
    u16*   descb = (u16*)(ws + 5 * (size_t)QS);
    float* bias1f = ws + (size_t)(5.5 * QS);      // 512 floats
    u16*   wpool = (u16*)(ws + 6 * (size_t)QS);
    u16*   vtb   = (u16*)(ws + (size_t)(6.5 * QS));
    u16* wqkvb = wpool;                       // 768*256 = 196608
    u16* w2b   = wqkvb + 196608;              // 256*512 = 131072
    u16* w1f   = w2b   + 131072;              // 512*512 = 262144 (fused W1')

    const dim3 blk(256);

    // 0) casts + W1 split + bias' fold + Wfused — one launch
    cast7_kernel<<<dim3(5696), blk, 0, stream>>>(
        desc, descb, Wqkv_w, wqkvb, Wo_w, W1_w, w1f, W2_w, w2b,
        W1_b, Wo_b, bias1f);

    // 1) QKV projection -> bf16 qkvb [M,768]
    gemm_bf16<4, 0, 0, 1><<<dim3(M_ / 128, 768 / 128), blk, 0, stream>>>(
        descb, nullptr, wqkvb, Wqkv_b, nullptr, nullptr, qkvb, 256, 768, 768);

    // 2) fused rope + V transpose -> qb, kb, vtb
    ropevt_kernel<<<dim3(B_ * H_, S_ / 128), blk, 0, stream>>>(
        qkvb, kp, qb, kb, vtb);

    // 3) flash attention v11 (double-buffered K, counted vmcnt) -> ctx bf16
    attn_kernel<<<dim3(B_ * H_, S_ / 128), blk, 0, stream>>>(qb, kb, vtb, ctxb);

    // 4) W1' on concat(descb, ctxb) -> bf16 x1b [M,512]   (Wo folded in)
    gemm_bf16<4, 1, 0, 1><<<dim3(M_ / 128, 512 / 128), blk, 0, stream>>>(
        descb, ctxb, w1f, bias1f, nullptr, nullptr, x1b, 512, 512, 512);

    // 5) LayerNorm + GELU (wave-per-row): bf16 in -> bf16 x1g
    ln_gelu_kernel<<<dim3(M_ / 4), blk, 0, stream>>>(x1b, ln_g, ln_b, x1g);

    // 6) W2 + bias + residual -> out fp32
    gemm_bf16<2, 0, 1, 0><<<dim3(M_ / 128, 256 / 64), blk, 0, stream>>>(
        x1g, nullptr, w2b, W2_b, desc, out, nullptr, 512, 256, 256);
}